// Round 9
// baseline (443.231 us; speedup 1.0000x reference)
//
#include <hip/hip_runtime.h>

// LSS view transform, chunked-gather formulation — ROUND 17 = MEASUREMENT (fix).
// Round-7 pipeline (140.7us, best) with x8 in-kernel repeat loops so each
// major kernel exceeds the 46us harness-poison floor and appears in rocprof
// top-5 with real counters. Rep 0 is byte-identical to round 7 (real buffers).
// ROUND-8 BUG FIXED: k_fill reps 1-7 now use a SCRATCH cursor (hist2_scr);
// rep 0 is the sole writer of the real cursor. Scratch slots clamped to
// [0, MAX_ENTRIES-1] (garbage cursor could go negative -> OOB into live ws).
// NEXT ROUND: strip reps, attack the measured top kernel.
constexpr int IMG_H = 48, IMG_W = 160;
constexpr int HW    = IMG_H * IMG_W;          // 7680
constexpr int BEV_H = 128, BEV_W = 128;
constexpr int NCELL = BEV_H * BEV_W;          // 16384 per batch
constexpr int C_DIM = 128, D_DIM = 64, B_DIM = 2;
constexpr int NCELL_TOT = B_DIM * NCELL;      // 32768
constexpr int NPIX_TOT  = B_DIM * HW;         // 15360
constexpr int NPTS      = NPIX_TOT * D_DIM;   // 983040
constexpr int MAX_ENTRIES = NPTS;
constexpr int CHUNK = 64;
constexpr int WAVES_PER_BLK = 4;
constexpr int NSHARD = 16;
constexpr int CNT_BLOCKS = NPTS / 256;        // 3840
constexpr int TRN_BLOCKS = (HW / 32) * (C_DIM / 32) * B_DIM;  // 1920
constexpr int SCAN_BLOCKS = NCELL_TOT / 256;  // 128
constexpr int PREP_REPS = 8, FILL_REPS = 8, GATH_REPS = 8, UNT_REPS = 8;
constexpr float X_MIN = -51.2f, Y_MIN = -51.2f;
constexpr float RES_X = 102.4f / 128.0f;
constexpr float RES_Y = 102.4f / 128.0f;

typedef _Float16 half2v __attribute__((ext_vector_type(2)));

// ---- ws layout (4-byte words); real ~28.8 MB + ~24 MB scratch ----
constexpr size_t WS_IMG_T = 0;                                      // half[B*HW*C]
constexpr size_t WS_FLAGS = WS_IMG_T + (size_t)B_DIM * HW * C_DIM / 2;  // uint[128] [memset]
constexpr size_t WS_HIST2 = WS_FLAGS + 128;                         // int[16*32768] [memset]
constexpr size_t WS_OUT_T = WS_HIST2 + (size_t)NSHARD * NCELL_TOT;  // float[32768*128] [memset, adjacent]
constexpr size_t WS_OFFS  = WS_OUT_T + (size_t)NCELL_TOT * C_DIM;   // int[32769]+pad
constexpr size_t WS_EKEY  = WS_OFFS + NCELL_TOT + 4;                // int[NPTS]
constexpr size_t WS_EW16  = WS_EKEY + MAX_ENTRIES;                  // ushort[NPTS]
// scratch (never zeroed; only reps 1..N-1 touch these; results discarded)
constexpr size_t WS_H2SCR = WS_EW16 + MAX_ENTRIES / 2;              // int[16*32768]
constexpr size_t WS_OTSCR = WS_H2SCR + (size_t)NSHARD * NCELL_TOT;  // float[32768*128]
constexpr size_t WS_EKSCR = WS_OTSCR + (size_t)NCELL_TOT * C_DIM;   // int[NPTS]
constexpr size_t WS_EWSCR = WS_EKSCR + MAX_ENTRIES;                 // ushort[NPTS]
constexpr size_t MEMSET_WORDS = 128 + (size_t)NSHARD * NCELL_TOT + (size_t)NCELL_TOT * C_DIM;

__device__ inline int point_shard(int tid) {
    return ((tid >> 2) + (tid >> 8)) & (NSHARD - 1);   // deterministic in tid
}

__device__ inline void make_ray(const float* __restrict__ K, int b, float gx, float gy,
                                float& rx, float& ry, float& rz) {
    const float* Kb = K + b * 9;
    const float a00 = Kb[0], a01 = Kb[1], a02 = Kb[2];
    const float a10 = Kb[3], a11 = Kb[4], a12 = Kb[5];
    const float a20 = Kb[6], a21 = Kb[7], a22 = Kb[8];
    const float det = a00 * (a11 * a22 - a12 * a21)
                    - a01 * (a10 * a22 - a12 * a20)
                    + a02 * (a10 * a21 - a11 * a20);
    const float inv = 1.0f / det;
    const float i00 =  (a11 * a22 - a12 * a21) * inv;
    const float i01 = -(a01 * a22 - a02 * a21) * inv;
    const float i02 =  (a01 * a12 - a02 * a11) * inv;
    const float i10 = -(a10 * a22 - a12 * a20) * inv;
    const float i11 =  (a00 * a22 - a02 * a20) * inv;
    const float i12 = -(a00 * a12 - a02 * a10) * inv;
    const float i20 =  (a10 * a21 - a11 * a20) * inv;
    const float i21 = -(a00 * a21 - a01 * a20) * inv;
    const float i22 =  (a00 * a11 - a01 * a10) * inv;
    rx = i00 * gx + i01 * gy + i02;
    ry = i10 * gx + i11 * gy + i12;
    rz = i20 * gx + i21 * gy + i22;
}

// Returns global cell id (b*NCELL + cell) or -1. tid = ((b*D + d)*HW + pix).
__device__ inline int point_gcell(int tid, const float* __restrict__ dv,
                                  const float* __restrict__ K,
                                  const float* __restrict__ T) {
    const int pix = tid % HW;
    const int bd  = tid / HW;
    const int d   = bd % D_DIM;
    const int b   = bd / D_DIM;
    const int h = pix / IMG_W, w = pix % IMG_W;
    float rx, ry, rz;
    make_ray(K, b, (float)w, (float)h, rx, ry, rz);
    const float* Tb = T + b * 16;
    const float dep = dv[d];                       // wave-uniform
    const float px = dep * rx, py = dep * ry, pz = dep * rz;
    const float x = Tb[0] * px + Tb[1] * py + Tb[2]  * pz + Tb[3];
    const float y = Tb[4] * px + Tb[5] * py + Tb[6]  * pz + Tb[7];
    const float z = Tb[8] * px + Tb[9] * py + Tb[10] * pz + Tb[11];
    const int bx = (int)((x - X_MIN) / RES_X);     // truncate-toward-zero == astype(int32)
    const int by = (int)((y - Y_MIN) / RES_Y);
    const bool valid = (bx >= 0) && (bx < BEV_W) && (by >= 0) && (by < BEV_H) && (z > 0.0f);
    return valid ? (b * NCELL + by * BEV_W + bx) : -1;
}

// Wave-run helpers: lanes are consecutive pixels -> equal-cell runs.
__device__ inline bool wave_runs(int gcell, int lane, int& run_len, int& leader_idx) {
    const int left = __shfl_up(gcell, 1);          // width 64
    const bool is_leader = (lane == 0) || (left != gcell);
    const unsigned long long lmask = __ballot(is_leader);
    const unsigned long long rest = (lane == 63) ? 0ULL : (lmask >> (lane + 1));
    const int f = __ffsll((unsigned long long)rest);   // 1+idx or 0
    run_len = f ? f : (64 - lane);
    const unsigned long long below =
        lmask & ((lane == 63) ? ~0ULL : ((1ULL << (lane + 1)) - 1ULL));
    leader_idx = 63 - __clzll((long long)below);
    return is_leader;
}

// ---- K1: fused {sharded count} + {transpose/fp16}; x PREP_REPS ----
// reps 1+ count into hist2_scr (discarded); img_t rewrites are identical-value.
__global__ __launch_bounds__(256) void k_prep(const float* __restrict__ img,
                                              _Float16* __restrict__ img_t,
                                              const float* __restrict__ dv,
                                              const float* __restrict__ K,
                                              const float* __restrict__ T,
                                              int* __restrict__ hist2,
                                              int* __restrict__ hist2_scr) {
    __shared__ float tile[32][33];
    for (int rep = 0; rep < PREP_REPS; ++rep) {
        asm volatile("" ::: "memory");
        int* __restrict__ h2 = (rep == 0) ? hist2 : hist2_scr;
        if (blockIdx.x < CNT_BLOCKS) {
            const int tid = blockIdx.x * 256 + threadIdx.x;   // < NPTS (exact)
            const int gcell = point_gcell(tid, dv, K, T);
            const int lane = threadIdx.x & 63;
            int run_len, leader_idx;
            const bool lead = wave_runs(gcell, lane, run_len, leader_idx);
            if (lead && gcell >= 0)
                atomicAdd(&h2[(size_t)point_shard(tid) * NCELL_TOT + gcell], run_len);
        } else {
            const int bi = blockIdx.x - CNT_BLOCKS;
            const int px_t = bi % (HW / 32);
            const int c_t  = (bi / (HW / 32)) % (C_DIM / 32);
            const int b    = bi / ((HW / 32) * (C_DIM / 32));
            const int tx = threadIdx.x & 31, ty = threadIdx.x >> 5;   // (32,8)
            const int pix0 = px_t * 32, c0 = c_t * 32;
            __syncthreads();                                  // tile reuse across reps
            #pragma unroll
            for (int j = 0; j < 32; j += 8)
                tile[ty + j][tx] = img[((size_t)(b * C_DIM + c0 + ty + j)) * HW + pix0 + tx];
            __syncthreads();
            #pragma unroll
            for (int j = 0; j < 32; j += 8)
                img_t[((size_t)(b * HW + pix0 + ty + j)) * C_DIM + c0 + tx] =
                    (_Float16)tile[tx][ty + j];
        }
    }
}

// ---- K2: fused shard-reduce + global exclusive scan (decoupled lookback) ----
__global__ __launch_bounds__(256) void k_scan_fused(int* __restrict__ hist2,
                                                    int* __restrict__ offs,
                                                    unsigned* __restrict__ flags) {
    __shared__ int lds[256];
    __shared__ int s_base;
    const int b = blockIdx.x;                      // 128 blocks
    const int t = threadIdx.x;                     // 256 threads
    const int cell = b * 256 + t;
    int run = 0;
    #pragma unroll
    for (int sh = 0; sh < NSHARD; ++sh) {
        const size_t idx = (size_t)sh * NCELL_TOT + cell;
        const int c = hist2[idx];
        hist2[idx] = run;
        run += c;
    }
    const int h = run;                             // cell total
    lds[t] = h;
    __syncthreads();
    #pragma unroll
    for (int off = 1; off < 256; off <<= 1) {
        const int v = (t >= off) ? lds[t - off] : 0;
        __syncthreads();
        lds[t] += v;
        __syncthreads();
    }
    const int incl = lds[t];
    const int S = lds[255];                        // block aggregate
    if (t == 0) {
        const unsigned w = (((b == 0) ? 2u : 1u) << 30) | (unsigned)S;
        __hip_atomic_store(&flags[b], w, __ATOMIC_RELEASE, __HIP_MEMORY_SCOPE_AGENT);
        if (b == 0) s_base = 0;
    }
    if (b > 0 && t < 64) {                         // wave-0 lookback
        int sum = 0;
        int p = b - 1;
        bool done = false;
        while (!done) {
            const int idx = p - t;
            unsigned w;
            if (idx >= 0) {
                do {
                    w = __hip_atomic_load(&flags[idx], __ATOMIC_ACQUIRE,
                                          __HIP_MEMORY_SCOPE_AGENT);
                } while ((w >> 30) == 0);
            } else {
                w = 2u << 30;                      // virtual predecessor: incl 0
            }
            const unsigned long long m2 = __ballot((w >> 30) == 2u);
            const int first2 = __ffsll(m2) - 1;    // nearest inclusive pred
            const int limit = (first2 < 0) ? 63 : first2;
            int contrib = (t <= limit && idx >= 0) ? (int)(w & 0x3FFFFFFFu) : 0;
            #pragma unroll
            for (int o = 32; o > 0; o >>= 1) contrib += __shfl_down(contrib, o);
            sum += __shfl(contrib, 0);
            if (first2 >= 0) done = true;
            else p -= 64;
        }
        if (t == 0) {
            s_base = sum;
            const unsigned w2 = (2u << 30) | (unsigned)(sum + S);
            __hip_atomic_store(&flags[b], w2, __ATOMIC_RELEASE, __HIP_MEMORY_SCOPE_AGENT);
        }
    }
    __syncthreads();
    const int base = s_base;
    offs[cell] = base + incl - h;                  // global exclusive prefix
    if (cell == NCELL_TOT - 1) offs[NCELL_TOT] = base + S;
}

// ---- K3: fill entries; x FILL_REPS.
// rep 0: real cursor (hist2) + real ekey/ew16 — byte-identical to round 7.
// reps 1+: SCRATCH cursor (hist2_scr, garbage ok) + scratch ekey/ew16,
// slot clamped both sides so garbage bases can't escape the scratch region.
__global__ __launch_bounds__(256) void k_fill(const float* __restrict__ dp,
                                              const float* __restrict__ dv,
                                              const float* __restrict__ K,
                                              const float* __restrict__ T,
                                              const int* __restrict__ offs,
                                              int* __restrict__ cursor2,     // real (= hist2)
                                              int* __restrict__ cursor2_scr, // scratch
                                              int* __restrict__ ekey,
                                              unsigned short* __restrict__ ew16,
                                              int* __restrict__ ekey_scr,
                                              unsigned short* __restrict__ ew16_scr) {
    const int tid = blockIdx.x * 256 + threadIdx.x;   // < NPTS (exact grid)
    const int lane = threadIdx.x & 63;
    for (int rep = 0; rep < FILL_REPS; ++rep) {
        asm volatile("" ::: "memory");
        int* __restrict__ cur = (rep == 0) ? cursor2 : cursor2_scr;
        const int gcell = point_gcell(tid, dv, K, T);
        int run_len, leader_idx;
        const bool lead = wave_runs(gcell, lane, run_len, leader_idx);
        int base = 0;
        if (lead && gcell >= 0)
            base = offs[gcell]
                 + atomicAdd(&cur[(size_t)point_shard(tid) * NCELL_TOT + gcell], run_len);
        base = __shfl(base, leader_idx);              // broadcast my run's base
        if (gcell >= 0) {
            int slot = base + (lane - leader_idx);
            const float p = dp[tid];                  // coalesced
            const int key = (gcell << 13) | (tid % HW);
            const unsigned short wq = (unsigned short)__float2uint_rn(p * 65535.0f);
            if (rep == 0) {
                ekey[slot] = key;                     // real path: exact round-7 writes
                ew16[slot] = wq;
            } else {
                slot = max(0, min(slot, MAX_ENTRIES - 1));   // confine to scratch
                ekey_scr[slot] = key;
                ew16_scr[slot] = wq;
            }
        }
    }
}

// ---- K4: chunked segmented reduction; x GATH_REPS (rep 0 -> out_t real).
// Inputs read-only across reps; reps 1+ flush to out_t_scr. Safe.
__global__ __launch_bounds__(256) void k_chunk_gather(
    const _Float16* __restrict__ img_t,
    const int* __restrict__ offs,     // offs[NCELL_TOT] = total entry count
    const int* __restrict__ ekey,
    const unsigned short* __restrict__ ew16,
    float* __restrict__ out_t,
    float* __restrict__ out_t_scr)
{
    const int total = offs[NCELL_TOT];
    const int wave  = threadIdx.x >> 6;
    const int lane  = threadIdx.x & 63;
    const int base  = (blockIdx.x * WAVES_PER_BLK + wave) * CHUNK;
    if (base >= total) return;
    const int c2 = lane * 2;                          // channels c2, c2+1

    for (int rep = 0; rep < GATH_REPS; ++rep) {
        asm volatile("" ::: "memory");
        float* __restrict__ tgt = (rep == 0) ? out_t : out_t_scr;
        // per-lane entry fetch (coalesced); pad = dup last key, weight 0
        const int eidx = min(base + lane, total - 1);
        const int   mykey = ekey[eidx];
        const float myw   = (base + lane < total)
                            ? (float)ew16[base + lane] * (1.0f / 65535.0f) : 0.0f;
        const int mywi = __float_as_int(myw);

        const int fc    = __builtin_amdgcn_readlane(mykey, 0) >> 13;   // first cell
        const int lcell = __builtin_amdgcn_readlane(mykey, 63) >> 13;  // last cell
        const bool shared_first = (base > 0) && ((ekey[base - 1] >> 13) == fc);
        const bool shared_last  = (base + CHUNK < total) && ((ekey[base + CHUNK] >> 13) == lcell);

        int prev = fc;
        float2 acc = make_float2(0.0f, 0.0f);

#define LOADG(g, V)                                                              \
    do {                                                                         \
        _Pragma("unroll")                                                        \
        for (int k = 0; k < 8; ++k) {                                            \
            const int key = __builtin_amdgcn_readlane(mykey, (g) * 8 + k);       \
            const int pix = key & 8191;                                          \
            const int bb  = key >> 27;                                           \
            V[k] = *reinterpret_cast<const half2v*>(                             \
                &img_t[((size_t)(bb * HW + pix)) * C_DIM + c2]);                 \
        }                                                                        \
    } while (0)

#define FLUSHP(cell)                                                             \
    do {                                                                         \
        float* o = &tgt[(size_t)(cell) * C_DIM + c2];                            \
        const bool shared_ = ((cell) == fc && shared_first) ||                   \
                             ((cell) == lcell && shared_last);                   \
        if (shared_) {                                                           \
            atomicAdd(o, acc.x);                                                 \
            atomicAdd(o + 1, acc.y);                                             \
        } else {                                                                 \
            *reinterpret_cast<float2*>(o) = acc;  /* exclusive owner */          \
        }                                                                        \
    } while (0)

#define ACCG(g, V)                                                               \
    do {                                                                         \
        _Pragma("unroll")                                                        \
        for (int k = 0; k < 8; ++k) {                                            \
            const int   key = __builtin_amdgcn_readlane(mykey, (g) * 8 + k);     \
            const float wgt =                                                    \
                __int_as_float(__builtin_amdgcn_readlane(mywi, (g) * 8 + k));    \
            const int gcell = key >> 13;                                         \
            if (gcell != prev) {                      /* scalar branch */        \
                FLUSHP(prev);                                                    \
                acc = make_float2(0.0f, 0.0f);                                   \
                prev = gcell;                                                    \
            }                                                                    \
            acc.x = fmaf((float)V[k][0], wgt, acc.x);                            \
            acc.y = fmaf((float)V[k][1], wgt, acc.y);                            \
        }                                                                        \
    } while (0)

        half2v va[8], vb[8];
        // modulo-2 software pipeline over 8 groups of 8 entries (CHUNK=64)
        LOADG(0, va);
        LOADG(1, vb);
        ACCG(0, va);
        LOADG(2, va);
        ACCG(1, vb);
        LOADG(3, vb);
        ACCG(2, va);
        LOADG(4, va);
        ACCG(3, vb);
        LOADG(5, vb);
        ACCG(4, va);
        LOADG(6, va);
        ACCG(5, vb);
        LOADG(7, vb);
        ACCG(6, va);
        ACCG(7, vb);
        FLUSHP(prev);

#undef LOADG
#undef FLUSHP
#undef ACCG
    }
}

// ---- K5: untranspose; x UNT_REPS (idempotent: same values rewritten) ----
__global__ __launch_bounds__(256) void k_untranspose(const float* __restrict__ out_t,
                                                     float* __restrict__ out) {
    __shared__ float tile[32][33];
    const int b = blockIdx.z;
    const int tx = threadIdx.x, ty = threadIdx.y;      // block (32, 8)
    const int cell0 = blockIdx.x * 32, c0 = blockIdx.y * 32;
    const float* src = out_t + (size_t)b * NCELL * C_DIM;
    for (int rep = 0; rep < UNT_REPS; ++rep) {
        asm volatile("" ::: "memory");
        __syncthreads();                               // tile reuse across reps
        #pragma unroll
        for (int j = 0; j < 32; j += 8)                // read: c contiguous
            tile[ty + j][tx] = src[((size_t)(cell0 + ty + j)) * C_DIM + c0 + tx];
        __syncthreads();
        #pragma unroll
        for (int j = 0; j < 32; j += 8)                // write: cell contiguous
            out[((size_t)(b * C_DIM + c0 + ty + j)) * NCELL + cell0 + tx] = tile[tx][ty + j];
    }
}

extern "C" void kernel_launch(void* const* d_in, const int* in_sizes, int n_in,
                              void* d_out, int out_size, void* d_ws, size_t ws_size,
                              hipStream_t stream) {
    const float* img = (const float*)d_in[0];
    const float* dp  = (const float*)d_in[1];
    const float* dv  = (const float*)d_in[2];
    const float* K   = (const float*)d_in[3];
    const float* T   = (const float*)d_in[4];
    float* out = (float*)d_out;

    _Float16* img_t = (_Float16*)d_ws;                  // WS_IMG_T == 0
    unsigned* flags = (unsigned*)((int*)d_ws + WS_FLAGS);
    int*   hist2  = (int*)d_ws + WS_HIST2;
    float* out_t  = (float*)d_ws + WS_OUT_T;
    int*   offs   = (int*)d_ws + WS_OFFS;
    int*   ekey   = (int*)d_ws + WS_EKEY;
    unsigned short* ew16 = (unsigned short*)((int*)d_ws + WS_EW16);
    int*   hist2_scr = (int*)d_ws + WS_H2SCR;
    float* out_t_scr = (float*)d_ws + WS_OTSCR;
    int*   ekey_scr  = (int*)d_ws + WS_EKSCR;
    unsigned short* ew16_scr = (unsigned short*)((int*)d_ws + WS_EWSCR);
    (void)ws_size;

    // zero flags + hist2 + out_t in one contiguous memset (~18.9 MB)
    hipMemsetAsync(flags, 0, MEMSET_WORDS * sizeof(int), stream);

    k_prep<<<CNT_BLOCKS + TRN_BLOCKS, 256, 0, stream>>>(img, img_t, dv, K, T,
                                                        hist2, hist2_scr);
    k_scan_fused<<<SCAN_BLOCKS, 256, 0, stream>>>(hist2, offs, flags);
    k_fill<<<NPTS / 256, 256, 0, stream>>>(dp, dv, K, T, offs, hist2, hist2_scr,
                                           ekey, ew16, ekey_scr, ew16_scr);
    constexpr int GATHER_BLOCKS = MAX_ENTRIES / (CHUNK * WAVES_PER_BLK);
    k_chunk_gather<<<GATHER_BLOCKS, 256, 0, stream>>>(img_t, offs, ekey, ew16,
                                                      out_t, out_t_scr);
    k_untranspose<<<dim3(NCELL / 32, C_DIM / 32, B_DIM), dim3(32, 8), 0, stream>>>(
        out_t, out);
}

// Round 10
// 328.024 us; speedup vs baseline: 1.3512x; 1.3512x over previous
//
#include <hip/hip_runtime.h>

// LSS view transform, chunked-gather formulation, sharded + wave-run binning.
// out[b,c,cell] = sum_{(pix,d)->cell} img[b,c,pix] * dp[b,d,pix]
// Round-18 (base = round-7, 140.7us). Measurement (R9) isolated: gather=23.7us
// (L2/L3-BW floor ~17us), prep+fill+untr=19.5us, scan+gaps=48.7us. Attack the
// gap pool by deleting nodes WITHOUT device fences (R6 falsified barriers):
//  - scan dispatch deleted: prep blocks take a ticket after their work; the
//    last 128 ticket-holders spin on done==TOTAL (one line, cheap) then run
//    the decoupled-lookback scan inline. All cross-block state via
//    device-scope atomics only — no __threadfence, deadlock-free.
//  - out_t zeroing folded into prep (1 float4/thread); memset 18.9MB -> 2.1MB.
//  - fill / gather / untranspose byte-identical to round 7.
constexpr int IMG_H = 48, IMG_W = 160;
constexpr int HW    = IMG_H * IMG_W;          // 7680
constexpr int BEV_H = 128, BEV_W = 128;
constexpr int NCELL = BEV_H * BEV_W;          // 16384 per batch
constexpr int C_DIM = 128, D_DIM = 64, B_DIM = 2;
constexpr int NCELL_TOT = B_DIM * NCELL;      // 32768
constexpr int NPIX_TOT  = B_DIM * HW;         // 15360
constexpr int NPTS      = NPIX_TOT * D_DIM;   // 983040
constexpr int MAX_ENTRIES = NPTS;
constexpr int CHUNK = 64;
constexpr int WAVES_PER_BLK = 4;
constexpr int NSHARD = 16;
constexpr int CNT_BLOCKS = NPTS / 256;        // 3840
constexpr int TRN_BLOCKS = (HW / 32) * (C_DIM / 32) * B_DIM;  // 1920
constexpr int PREP_TOTAL = CNT_BLOCKS + TRN_BLOCKS;           // 5760
constexpr int SCAN_ROLES = 128;               // last 128 finishers run the scan
constexpr float X_MIN = -51.2f, Y_MIN = -51.2f;
constexpr float RES_X = 102.4f / 128.0f;
constexpr float RES_Y = 102.4f / 128.0f;

typedef _Float16 half2v __attribute__((ext_vector_type(2)));

// ---- ws layout (4-byte words), ~28.8 MB total ----
constexpr size_t WS_IMG_T = 0;                                      // half[B*HW*C]
constexpr size_t WS_DONE  = WS_IMG_T + (size_t)B_DIM * HW * C_DIM / 2;  // int[4]   [memset]
constexpr size_t WS_FLAGS = WS_DONE + 4;                            // uint[128]  [memset]
constexpr size_t WS_HIST2 = WS_FLAGS + 128;                         // int[16*32768] [memset]
constexpr size_t WS_OUT_T = WS_HIST2 + (size_t)NSHARD * NCELL_TOT;  // float[32768*128] (zeroed by prep)
constexpr size_t WS_OFFS  = WS_OUT_T + (size_t)NCELL_TOT * C_DIM;   // int[32769]+pad
constexpr size_t WS_EKEY  = WS_OFFS + NCELL_TOT + 4;                // int[NPTS]
constexpr size_t WS_EW16  = WS_EKEY + MAX_ENTRIES;                  // ushort[NPTS]
constexpr size_t MEMSET_WORDS = 4 + 128 + (size_t)NSHARD * NCELL_TOT;   // ~2.1 MB
constexpr int OUT_T_F4 = NCELL_TOT * C_DIM / 4;                     // 1048576 float4s

__device__ inline int point_shard(int tid) {
    return ((tid >> 2) + (tid >> 8)) & (NSHARD - 1);   // deterministic in tid
}

__device__ inline void make_ray(const float* __restrict__ K, int b, float gx, float gy,
                                float& rx, float& ry, float& rz) {
    const float* Kb = K + b * 9;
    const float a00 = Kb[0], a01 = Kb[1], a02 = Kb[2];
    const float a10 = Kb[3], a11 = Kb[4], a12 = Kb[5];
    const float a20 = Kb[6], a21 = Kb[7], a22 = Kb[8];
    const float det = a00 * (a11 * a22 - a12 * a21)
                    - a01 * (a10 * a22 - a12 * a20)
                    + a02 * (a10 * a21 - a11 * a20);
    const float inv = 1.0f / det;
    const float i00 =  (a11 * a22 - a12 * a21) * inv;
    const float i01 = -(a01 * a22 - a02 * a21) * inv;
    const float i02 =  (a01 * a12 - a02 * a11) * inv;
    const float i10 = -(a10 * a22 - a12 * a20) * inv;
    const float i11 =  (a00 * a22 - a02 * a20) * inv;
    const float i12 = -(a00 * a12 - a02 * a10) * inv;
    const float i20 =  (a10 * a21 - a11 * a20) * inv;
    const float i21 = -(a00 * a21 - a01 * a20) * inv;
    const float i22 =  (a00 * a11 - a01 * a10) * inv;
    rx = i00 * gx + i01 * gy + i02;
    ry = i10 * gx + i11 * gy + i12;
    rz = i20 * gx + i21 * gy + i22;
}

// Returns global cell id (b*NCELL + cell) or -1. tid = ((b*D + d)*HW + pix).
__device__ inline int point_gcell(int tid, const float* __restrict__ dv,
                                  const float* __restrict__ K,
                                  const float* __restrict__ T) {
    const int pix = tid % HW;
    const int bd  = tid / HW;
    const int d   = bd % D_DIM;
    const int b   = bd / D_DIM;
    const int h = pix / IMG_W, w = pix % IMG_W;
    float rx, ry, rz;
    make_ray(K, b, (float)w, (float)h, rx, ry, rz);
    const float* Tb = T + b * 16;
    const float dep = dv[d];                       // wave-uniform
    const float px = dep * rx, py = dep * ry, pz = dep * rz;
    const float x = Tb[0] * px + Tb[1] * py + Tb[2]  * pz + Tb[3];
    const float y = Tb[4] * px + Tb[5] * py + Tb[6]  * pz + Tb[7];
    const float z = Tb[8] * px + Tb[9] * py + Tb[10] * pz + Tb[11];
    const int bx = (int)((x - X_MIN) / RES_X);     // truncate-toward-zero == astype(int32)
    const int by = (int)((y - Y_MIN) / RES_Y);
    const bool valid = (bx >= 0) && (bx < BEV_W) && (by >= 0) && (by < BEV_H) && (z > 0.0f);
    return valid ? (b * NCELL + by * BEV_W + bx) : -1;
}

// Wave-run helpers: lanes are consecutive pixels -> equal-cell runs.
__device__ inline bool wave_runs(int gcell, int lane, int& run_len, int& leader_idx) {
    const int left = __shfl_up(gcell, 1);          // width 64
    const bool is_leader = (lane == 0) || (left != gcell);
    const unsigned long long lmask = __ballot(is_leader);
    const unsigned long long rest = (lane == 63) ? 0ULL : (lmask >> (lane + 1));
    const int f = __ffsll((unsigned long long)rest);   // 1+idx or 0
    run_len = f ? f : (64 - lane);
    const unsigned long long below =
        lmask & ((lane == 63) ? ~0ULL : ((1ULL << (lane + 1)) - 1ULL));
    leader_idx = 63 - __clzll((long long)below);
    return is_leader;
}

// ---- K1: fused {sharded count | transpose/fp16 | out_t zero} + inline scan.
// After its unit, each block tickets `done` (ACQ_REL). The last SCAN_ROLES
// ticket-holders spin until done==PREP_TOTAL (all counts released), then run
// the decoupled-lookback scan. hist2 counts are produced AND consumed through
// device-scope atomics -> no fence needed, no barrier, deadlock-free.
__global__ __launch_bounds__(256) void k_prep(const float* __restrict__ img,
                                              _Float16* __restrict__ img_t,
                                              const float* __restrict__ dv,
                                              const float* __restrict__ K,
                                              const float* __restrict__ T,
                                              int* __restrict__ hist2,
                                              float4* __restrict__ out_t4,
                                              int* __restrict__ done,
                                              unsigned* __restrict__ flags,
                                              int* __restrict__ offs) {
    __shared__ float tile[32][33];
    __shared__ int lds[256];
    __shared__ int s_role;
    __shared__ int s_base;
    const int t = threadIdx.x;

    // zero out_t stripe (grid covers all of it; <=1 float4 per thread)
    {
        const int i = blockIdx.x * 256 + t;
        if (i < OUT_T_F4) out_t4[i] = make_float4(0.f, 0.f, 0.f, 0.f);
    }

    if (blockIdx.x < CNT_BLOCKS) {
        const int tid = blockIdx.x * 256 + t;             // < NPTS (exact)
        const int gcell = point_gcell(tid, dv, K, T);
        const int lane = t & 63;
        int run_len, leader_idx;
        const bool lead = wave_runs(gcell, lane, run_len, leader_idx);
        if (lead && gcell >= 0)
            atomicAdd(&hist2[(size_t)point_shard(tid) * NCELL_TOT + gcell], run_len);
    } else {
        const int bi = blockIdx.x - CNT_BLOCKS;
        const int px_t = bi % (HW / 32);
        const int c_t  = (bi / (HW / 32)) % (C_DIM / 32);
        const int b    = bi / ((HW / 32) * (C_DIM / 32));
        const int tx = t & 31, ty = t >> 5;               // (32,8)
        const int pix0 = px_t * 32, c0 = c_t * 32;
        #pragma unroll
        for (int j = 0; j < 32; j += 8)
            tile[ty + j][tx] = img[((size_t)(b * C_DIM + c0 + ty + j)) * HW + pix0 + tx];
        __syncthreads();
        #pragma unroll
        for (int j = 0; j < 32; j += 8)
            img_t[((size_t)(b * HW + pix0 + ty + j)) * C_DIM + c0 + tx] =
                (_Float16)tile[tx][ty + j];
    }

    // ---- ticket: elect last SCAN_ROLES finishers ----
    if (t == 0) {
        const int tk = __hip_atomic_fetch_add(done, 1, __ATOMIC_ACQ_REL,
                                              __HIP_MEMORY_SCOPE_AGENT);
        s_role = tk - (PREP_TOTAL - SCAN_ROLES);
        if (s_role >= 0) {
            // wait until every block's counts are released (done == PREP_TOTAL)
            while (__hip_atomic_load(done, __ATOMIC_ACQUIRE,
                                     __HIP_MEMORY_SCOPE_AGENT) < PREP_TOTAL)
                __builtin_amdgcn_s_sleep(1);
        }
    }
    __syncthreads();
    const int role = s_role;                              // scan block id 0..127
    if (role < 0) return;

    // ---- inline scan (decoupled lookback), b = role ----
    const int cell = role * 256 + t;
    int run = 0;
    #pragma unroll
    for (int sh = 0; sh < NSHARD; ++sh) {
        const size_t idx = (size_t)sh * NCELL_TOT + cell;
        // counts were produced by device-scope atomics -> read at coherent point
        const int c = __hip_atomic_load(&hist2[idx], __ATOMIC_RELAXED,
                                        __HIP_MEMORY_SCOPE_AGENT);
        hist2[idx] = run;          // local exclusive prefix (read next dispatch)
        run += c;
    }
    const int h = run;                                    // cell total
    lds[t] = h;
    __syncthreads();
    #pragma unroll
    for (int off = 1; off < 256; off <<= 1) {
        const int v = (t >= off) ? lds[t - off] : 0;
        __syncthreads();
        lds[t] += v;
        __syncthreads();
    }
    const int incl = lds[t];
    const int S = lds[255];                               // block aggregate
    if (t == 0) {
        const unsigned w = (((role == 0) ? 2u : 1u) << 30) | (unsigned)S;
        __hip_atomic_store(&flags[role], w, __ATOMIC_RELEASE, __HIP_MEMORY_SCOPE_AGENT);
        if (role == 0) s_base = 0;
    }
    if (role > 0 && t < 64) {                             // wave-0 lookback
        int sum = 0;
        int p = role - 1;
        bool done2 = false;
        while (!done2) {
            const int idx = p - t;
            unsigned w;
            if (idx >= 0) {
                do {
                    w = __hip_atomic_load(&flags[idx], __ATOMIC_ACQUIRE,
                                          __HIP_MEMORY_SCOPE_AGENT);
                } while ((w >> 30) == 0);
            } else {
                w = 2u << 30;                             // virtual pred: incl 0
            }
            const unsigned long long m2 = __ballot((w >> 30) == 2u);
            const int first2 = __ffsll(m2) - 1;           // nearest inclusive pred
            const int limit = (first2 < 0) ? 63 : first2;
            int contrib = (t <= limit && idx >= 0) ? (int)(w & 0x3FFFFFFFu) : 0;
            #pragma unroll
            for (int o = 32; o > 0; o >>= 1) contrib += __shfl_down(contrib, o);
            sum += __shfl(contrib, 0);
            if (first2 >= 0) done2 = true;
            else p -= 64;
        }
        if (t == 0) {
            s_base = sum;
            const unsigned w2 = (2u << 30) | (unsigned)(sum + S);
            __hip_atomic_store(&flags[role], w2, __ATOMIC_RELEASE, __HIP_MEMORY_SCOPE_AGENT);
        }
    }
    __syncthreads();
    const int base = s_base;
    offs[cell] = base + incl - h;                         // global exclusive prefix
    if (cell == NCELL_TOT - 1) offs[NCELL_TOT] = base + S;
}

// ---- K2: fill entries; leader reserves span via offs + local shard cursor ----
__global__ __launch_bounds__(256) void k_fill(const float* __restrict__ dp,
                                              const float* __restrict__ dv,
                                              const float* __restrict__ K,
                                              const float* __restrict__ T,
                                              const int* __restrict__ offs,
                                              int* __restrict__ cursor2,   // = hist2 (local prefix)
                                              int* __restrict__ ekey,
                                              unsigned short* __restrict__ ew16) {
    const int tid = blockIdx.x * 256 + threadIdx.x;   // < NPTS (exact grid)
    const int gcell = point_gcell(tid, dv, K, T);
    const int lane = threadIdx.x & 63;
    int run_len, leader_idx;
    const bool lead = wave_runs(gcell, lane, run_len, leader_idx);
    int base = 0;
    if (lead && gcell >= 0)
        base = offs[gcell]
             + atomicAdd(&cursor2[(size_t)point_shard(tid) * NCELL_TOT + gcell], run_len);
    base = __shfl(base, leader_idx);                  // broadcast my run's base
    if (gcell < 0) return;
    const int slot = base + (lane - leader_idx);      // contiguous, coalesced writes
    const float p = dp[tid];                          // tid == ((b*D+d)*HW+pix): coalesced
    ekey[slot] = (gcell << 13) | (tid % HW);
    ew16[slot] = (unsigned short)__float2uint_rn(p * 65535.0f);
}

// ---- K3: chunked segmented reduction. 4 waves/block, wave = one 64-entry
// chunk, thread = 2 channels. readlane broadcasts (SGPR path). Flush:
// cells wholly owned by this chunk -> plain float2 store; cells continued
// across a chunk boundary -> atomicAdd. Byte-identical to round 7.
__global__ __launch_bounds__(256) void k_chunk_gather(
    const _Float16* __restrict__ img_t,
    const int* __restrict__ offs,     // offs[NCELL_TOT] = total entry count
    const int* __restrict__ ekey,
    const unsigned short* __restrict__ ew16,
    float* __restrict__ out_t)
{
    const int total = offs[NCELL_TOT];
    const int wave  = threadIdx.x >> 6;
    const int lane  = threadIdx.x & 63;
    const int base  = (blockIdx.x * WAVES_PER_BLK + wave) * CHUNK;
    if (base >= total) return;

    // per-lane entry fetch (coalesced); pad = dup last key, weight 0
    const int eidx = min(base + lane, total - 1);
    const int   mykey = ekey[eidx];
    const float myw   = (base + lane < total)
                        ? (float)ew16[base + lane] * (1.0f / 65535.0f) : 0.0f;
    const int mywi = __float_as_int(myw);

    const int c2 = lane * 2;                          // channels c2, c2+1
    const int fc    = __builtin_amdgcn_readlane(mykey, 0) >> 13;   // first cell
    const int lcell = __builtin_amdgcn_readlane(mykey, 63) >> 13;  // last cell
    // boundary-continuation flags (uniform scalar loads, broadcast by cache)
    const bool shared_first = (base > 0) && ((ekey[base - 1] >> 13) == fc);
    const bool shared_last  = (base + CHUNK < total) && ((ekey[base + CHUNK] >> 13) == lcell);

    int prev = fc;
    float2 acc = make_float2(0.0f, 0.0f);

#define LOADG(g, V)                                                              \
    do {                                                                         \
        _Pragma("unroll")                                                        \
        for (int k = 0; k < 8; ++k) {                                            \
            const int key = __builtin_amdgcn_readlane(mykey, (g) * 8 + k);       \
            const int pix = key & 8191;                                          \
            const int bb  = key >> 27;                                           \
            V[k] = *reinterpret_cast<const half2v*>(                             \
                &img_t[((size_t)(bb * HW + pix)) * C_DIM + c2]);                 \
        }                                                                        \
    } while (0)

#define FLUSHP(cell)                                                             \
    do {                                                                         \
        float* o = &out_t[(size_t)(cell) * C_DIM + c2];                          \
        const bool shared_ = ((cell) == fc && shared_first) ||                   \
                             ((cell) == lcell && shared_last);                   \
        if (shared_) {                                                           \
            atomicAdd(o, acc.x);                                                 \
            atomicAdd(o + 1, acc.y);                                             \
        } else {                                                                 \
            *reinterpret_cast<float2*>(o) = acc;  /* exclusive owner */          \
        }                                                                        \
    } while (0)

#define ACCG(g, V)                                                               \
    do {                                                                         \
        _Pragma("unroll")                                                        \
        for (int k = 0; k < 8; ++k) {                                            \
            const int   key = __builtin_amdgcn_readlane(mykey, (g) * 8 + k);     \
            const float wgt =                                                    \
                __int_as_float(__builtin_amdgcn_readlane(mywi, (g) * 8 + k));    \
            const int gcell = key >> 13;                                         \
            if (gcell != prev) {                      /* scalar branch */        \
                FLUSHP(prev);                                                    \
                acc = make_float2(0.0f, 0.0f);                                   \
                prev = gcell;                                                    \
            }                                                                    \
            acc.x = fmaf((float)V[k][0], wgt, acc.x);                            \
            acc.y = fmaf((float)V[k][1], wgt, acc.y);                            \
        }                                                                        \
    } while (0)

    half2v va[8], vb[8];
    // modulo-2 software pipeline over 8 groups of 8 entries (CHUNK=64)
    LOADG(0, va);
    LOADG(1, vb);
    ACCG(0, va);
    LOADG(2, va);
    ACCG(1, vb);
    LOADG(3, vb);
    ACCG(2, va);
    LOADG(4, va);
    ACCG(3, vb);
    LOADG(5, vb);
    ACCG(4, va);
    LOADG(6, va);
    ACCG(5, vb);
    LOADG(7, vb);
    ACCG(6, va);
    ACCG(7, vb);
    FLUSHP(prev);

#undef LOADG
#undef FLUSHP
#undef ACCG
}

// ---- K4: untranspose out_t[b][cell][c] -> out[b][c][cell] ----
__global__ __launch_bounds__(256) void k_untranspose(const float* __restrict__ out_t,
                                                     float* __restrict__ out) {
    __shared__ float tile[32][33];
    const int b = blockIdx.z;
    const int tx = threadIdx.x, ty = threadIdx.y;      // block (32, 8)
    const int cell0 = blockIdx.x * 32, c0 = blockIdx.y * 32;
    const float* src = out_t + (size_t)b * NCELL * C_DIM;
    #pragma unroll
    for (int j = 0; j < 32; j += 8)                    // read: c contiguous
        tile[ty + j][tx] = src[((size_t)(cell0 + ty + j)) * C_DIM + c0 + tx];
    __syncthreads();
    #pragma unroll
    for (int j = 0; j < 32; j += 8)                    // write: cell contiguous
        out[((size_t)(b * C_DIM + c0 + ty + j)) * NCELL + cell0 + tx] = tile[tx][ty + j];
}

extern "C" void kernel_launch(void* const* d_in, const int* in_sizes, int n_in,
                              void* d_out, int out_size, void* d_ws, size_t ws_size,
                              hipStream_t stream) {
    const float* img = (const float*)d_in[0];
    const float* dp  = (const float*)d_in[1];
    const float* dv  = (const float*)d_in[2];
    const float* K   = (const float*)d_in[3];
    const float* T   = (const float*)d_in[4];
    float* out = (float*)d_out;

    _Float16* img_t = (_Float16*)d_ws;                  // WS_IMG_T == 0
    int*   done   = (int*)d_ws + WS_DONE;
    unsigned* flags = (unsigned*)((int*)d_ws + WS_FLAGS);
    int*   hist2  = (int*)d_ws + WS_HIST2;
    float* out_t  = (float*)d_ws + WS_OUT_T;
    int*   offs   = (int*)d_ws + WS_OFFS;
    int*   ekey   = (int*)d_ws + WS_EKEY;
    unsigned short* ew16 = (unsigned short*)((int*)d_ws + WS_EW16);
    (void)ws_size;

    // zero done + flags + hist2 (contiguous, ~2.1 MB); out_t zeroed by k_prep
    hipMemsetAsync(done, 0, MEMSET_WORDS * sizeof(int), stream);

    k_prep<<<PREP_TOTAL, 256, 0, stream>>>(img, img_t, dv, K, T, hist2,
                                           (float4*)out_t, done, flags, offs);
    k_fill<<<NPTS / 256, 256, 0, stream>>>(dp, dv, K, T, offs, hist2, ekey, ew16);
    constexpr int GATHER_BLOCKS = MAX_ENTRIES / (CHUNK * WAVES_PER_BLK);
    k_chunk_gather<<<GATHER_BLOCKS, 256, 0, stream>>>(img_t, offs, ekey, ew16, out_t);
    k_untranspose<<<dim3(NCELL / 32, C_DIM / 32, B_DIM), dim3(32, 8), 0, stream>>>(
        out_t, out);
}

// Round 11
// 141.017 us; speedup vs baseline: 3.1431x; 2.3261x over previous
//
#include <hip/hip_runtime.h>

// LSS view transform, chunked-gather formulation, sharded + wave-run binning.
// out[b,c,cell] = sum_{(pix,d)->cell} img[b,c,pix] * dp[b,d,pix]
// Round-19 (base = round-7, 140.7us best).
// R10 lesson (2x confirmed w/ R6): ordered (acquire/release) agent-scope
// atomics serialize ~50ns each at the cross-XCD coherence point -> any
// intra-kernel cross-block waiting is a tarpit. Relaxed device-scope atomics
// are cheap. Therefore:
//  - k_scan_fused's decoupled lookback (ACQUIRE polls + RELEASE flags) is
//    replaced by ARRIVAL-ORDER bases: entry ranges need disjointness, not
//    cell order. Each block claims base = atomicAdd(&tot, S_b) (relaxed);
//    128th arriver publishes offs[NCELL_TOT]. Zero ordered atomics.
//  - out_t zeroing folded into prep (R10-proven safe); memset 18.9->2.1MB.
//  - fill / gather / untranspose byte-identical to round 7.
constexpr int IMG_H = 48, IMG_W = 160;
constexpr int HW    = IMG_H * IMG_W;          // 7680
constexpr int BEV_H = 128, BEV_W = 128;
constexpr int NCELL = BEV_H * BEV_W;          // 16384 per batch
constexpr int C_DIM = 128, D_DIM = 64, B_DIM = 2;
constexpr int NCELL_TOT = B_DIM * NCELL;      // 32768
constexpr int NPIX_TOT  = B_DIM * HW;         // 15360
constexpr int NPTS      = NPIX_TOT * D_DIM;   // 983040
constexpr int MAX_ENTRIES = NPTS;
constexpr int CHUNK = 64;
constexpr int WAVES_PER_BLK = 4;
constexpr int NSHARD = 16;
constexpr int CNT_BLOCKS = NPTS / 256;        // 3840
constexpr int TRN_BLOCKS = (HW / 32) * (C_DIM / 32) * B_DIM;  // 1920
constexpr int PREP_TOTAL = CNT_BLOCKS + TRN_BLOCKS;           // 5760
constexpr int SCAN_BLOCKS = NCELL_TOT / 256;  // 128
constexpr float X_MIN = -51.2f, Y_MIN = -51.2f;
constexpr float RES_X = 102.4f / 128.0f;
constexpr float RES_Y = 102.4f / 128.0f;

typedef _Float16 half2v __attribute__((ext_vector_type(2)));

// ---- ws layout (4-byte words), ~28.8 MB total ----
constexpr size_t WS_IMG_T = 0;                                      // half[B*HW*C]
constexpr size_t WS_TOT   = WS_IMG_T + (size_t)B_DIM * HW * C_DIM / 2;  // int[4] [memset]
constexpr size_t WS_HIST2 = WS_TOT + 4;                             // int[16*32768] [memset, adjacent]
constexpr size_t WS_OUT_T = WS_HIST2 + (size_t)NSHARD * NCELL_TOT;  // float[32768*128] (zeroed by prep)
constexpr size_t WS_OFFS  = WS_OUT_T + (size_t)NCELL_TOT * C_DIM;   // int[32769]+pad
constexpr size_t WS_EKEY  = WS_OFFS + NCELL_TOT + 4;                // int[NPTS]
constexpr size_t WS_EW16  = WS_EKEY + MAX_ENTRIES;                  // ushort[NPTS]
constexpr size_t MEMSET_WORDS = 4 + (size_t)NSHARD * NCELL_TOT;     // ~2.1 MB
constexpr int OUT_T_F4 = NCELL_TOT * C_DIM / 4;                     // 1048576 float4s

__device__ inline int point_shard(int tid) {
    return ((tid >> 2) + (tid >> 8)) & (NSHARD - 1);   // deterministic in tid
}

__device__ inline void make_ray(const float* __restrict__ K, int b, float gx, float gy,
                                float& rx, float& ry, float& rz) {
    const float* Kb = K + b * 9;
    const float a00 = Kb[0], a01 = Kb[1], a02 = Kb[2];
    const float a10 = Kb[3], a11 = Kb[4], a12 = Kb[5];
    const float a20 = Kb[6], a21 = Kb[7], a22 = Kb[8];
    const float det = a00 * (a11 * a22 - a12 * a21)
                    - a01 * (a10 * a22 - a12 * a20)
                    + a02 * (a10 * a21 - a11 * a20);
    const float inv = 1.0f / det;
    const float i00 =  (a11 * a22 - a12 * a21) * inv;
    const float i01 = -(a01 * a22 - a02 * a21) * inv;
    const float i02 =  (a01 * a12 - a02 * a11) * inv;
    const float i10 = -(a10 * a22 - a12 * a20) * inv;
    const float i11 =  (a00 * a22 - a02 * a20) * inv;
    const float i12 = -(a00 * a12 - a02 * a10) * inv;
    const float i20 =  (a10 * a21 - a11 * a20) * inv;
    const float i21 = -(a00 * a21 - a01 * a20) * inv;
    const float i22 =  (a00 * a11 - a01 * a10) * inv;
    rx = i00 * gx + i01 * gy + i02;
    ry = i10 * gx + i11 * gy + i12;
    rz = i20 * gx + i21 * gy + i22;
}

// Returns global cell id (b*NCELL + cell) or -1. tid = ((b*D + d)*HW + pix).
__device__ inline int point_gcell(int tid, const float* __restrict__ dv,
                                  const float* __restrict__ K,
                                  const float* __restrict__ T) {
    const int pix = tid % HW;
    const int bd  = tid / HW;
    const int d   = bd % D_DIM;
    const int b   = bd / D_DIM;
    const int h = pix / IMG_W, w = pix % IMG_W;
    float rx, ry, rz;
    make_ray(K, b, (float)w, (float)h, rx, ry, rz);
    const float* Tb = T + b * 16;
    const float dep = dv[d];                       // wave-uniform
    const float px = dep * rx, py = dep * ry, pz = dep * rz;
    const float x = Tb[0] * px + Tb[1] * py + Tb[2]  * pz + Tb[3];
    const float y = Tb[4] * px + Tb[5] * py + Tb[6]  * pz + Tb[7];
    const float z = Tb[8] * px + Tb[9] * py + Tb[10] * pz + Tb[11];
    const int bx = (int)((x - X_MIN) / RES_X);     // truncate-toward-zero == astype(int32)
    const int by = (int)((y - Y_MIN) / RES_Y);
    const bool valid = (bx >= 0) && (bx < BEV_W) && (by >= 0) && (by < BEV_H) && (z > 0.0f);
    return valid ? (b * NCELL + by * BEV_W + bx) : -1;
}

// Wave-run helpers: lanes are consecutive pixels -> equal-cell runs.
__device__ inline bool wave_runs(int gcell, int lane, int& run_len, int& leader_idx) {
    const int left = __shfl_up(gcell, 1);          // width 64
    const bool is_leader = (lane == 0) || (left != gcell);
    const unsigned long long lmask = __ballot(is_leader);
    const unsigned long long rest = (lane == 63) ? 0ULL : (lmask >> (lane + 1));
    const int f = __ffsll((unsigned long long)rest);   // 1+idx or 0
    run_len = f ? f : (64 - lane);
    const unsigned long long below =
        lmask & ((lane == 63) ? ~0ULL : ((1ULL << (lane + 1)) - 1ULL));
    leader_idx = 63 - __clzll((long long)below);
    return is_leader;
}

// ---- K1: fused {sharded count | transpose/fp16 | out_t zero} ----
__global__ __launch_bounds__(256) void k_prep(const float* __restrict__ img,
                                              _Float16* __restrict__ img_t,
                                              const float* __restrict__ dv,
                                              const float* __restrict__ K,
                                              const float* __restrict__ T,
                                              int* __restrict__ hist2,
                                              float4* __restrict__ out_t4) {
    __shared__ float tile[32][33];
    const int t = threadIdx.x;

    // zero out_t stripe (grid covers all of it; <=1 float4 per thread)
    {
        const int i = blockIdx.x * 256 + t;
        if (i < OUT_T_F4) out_t4[i] = make_float4(0.f, 0.f, 0.f, 0.f);
    }

    if (blockIdx.x < CNT_BLOCKS) {
        const int tid = blockIdx.x * 256 + t;             // < NPTS (exact)
        const int gcell = point_gcell(tid, dv, K, T);
        const int lane = t & 63;
        int run_len, leader_idx;
        const bool lead = wave_runs(gcell, lane, run_len, leader_idx);
        if (lead && gcell >= 0)
            atomicAdd(&hist2[(size_t)point_shard(tid) * NCELL_TOT + gcell], run_len);
    } else {
        const int bi = blockIdx.x - CNT_BLOCKS;
        const int px_t = bi % (HW / 32);
        const int c_t  = (bi / (HW / 32)) % (C_DIM / 32);
        const int b    = bi / ((HW / 32) * (C_DIM / 32));
        const int tx = t & 31, ty = t >> 5;               // (32,8)
        const int pix0 = px_t * 32, c0 = c_t * 32;
        #pragma unroll
        for (int j = 0; j < 32; j += 8)
            tile[ty + j][tx] = img[((size_t)(b * C_DIM + c0 + ty + j)) * HW + pix0 + tx];
        __syncthreads();
        #pragma unroll
        for (int j = 0; j < 32; j += 8)
            img_t[((size_t)(b * HW + pix0 + ty + j)) * C_DIM + c0 + tx] =
                (_Float16)tile[tx][ty + j];
    }
}

// ---- K2: fence-free scan. Shard-reduce + in-place local prefix; block scan;
// base claimed in ARRIVAL order via relaxed atomicAdd (entry ranges need
// disjointness, not cell order). 128th arriver publishes offs[NCELL_TOT].
// tot[0]=running total, tot[1]=arrival count (same cache line -> L2
// serializes each block's two adds in order, so the last arrival's re-read
// of tot[0] sees all 128 contributions).
__global__ __launch_bounds__(256) void k_scan(int* __restrict__ hist2,
                                              int* __restrict__ offs,
                                              int* __restrict__ tot) {
    __shared__ int lds[256];
    __shared__ int s_base;
    const int b = blockIdx.x;                      // 128 blocks
    const int t = threadIdx.x;                     // 256 threads
    const int cell = b * 256 + t;
    // shard reduce + in-place local exclusive prefix (coalesced sweeps)
    int run = 0;
    #pragma unroll
    for (int sh = 0; sh < NSHARD; ++sh) {
        const size_t idx = (size_t)sh * NCELL_TOT + cell;
        const int c = hist2[idx];
        hist2[idx] = run;          // local exclusive prefix (cursor base for fill)
        run += c;
    }
    const int h = run;                             // cell total
    // inclusive block scan
    lds[t] = h;
    __syncthreads();
    #pragma unroll
    for (int off = 1; off < 256; off <<= 1) {
        const int v = (t >= off) ? lds[t - off] : 0;
        __syncthreads();
        lds[t] += v;
        __syncthreads();
    }
    const int incl = lds[t];
    const int S = lds[255];                        // block aggregate
    if (t == 0) {
        s_base = atomicAdd(&tot[0], S);            // relaxed, arrival order
        const int arr = atomicAdd(&tot[1], 1);
        if (arr == SCAN_BLOCKS - 1)                // last arrival: all adds landed
            offs[NCELL_TOT] = atomicAdd(&tot[0], 0);   // read final total
    }
    __syncthreads();
    offs[cell] = s_base + incl - h;                // global exclusive prefix
}

// ---- K3: fill entries; leader reserves span via offs + local shard cursor ----
__global__ __launch_bounds__(256) void k_fill(const float* __restrict__ dp,
                                              const float* __restrict__ dv,
                                              const float* __restrict__ K,
                                              const float* __restrict__ T,
                                              const int* __restrict__ offs,
                                              int* __restrict__ cursor2,   // = hist2 (local prefix)
                                              int* __restrict__ ekey,
                                              unsigned short* __restrict__ ew16) {
    const int tid = blockIdx.x * 256 + threadIdx.x;   // < NPTS (exact grid)
    const int gcell = point_gcell(tid, dv, K, T);
    const int lane = threadIdx.x & 63;
    int run_len, leader_idx;
    const bool lead = wave_runs(gcell, lane, run_len, leader_idx);
    int base = 0;
    if (lead && gcell >= 0)
        base = offs[gcell]
             + atomicAdd(&cursor2[(size_t)point_shard(tid) * NCELL_TOT + gcell], run_len);
    base = __shfl(base, leader_idx);                  // broadcast my run's base
    if (gcell < 0) return;
    const int slot = base + (lane - leader_idx);      // contiguous, coalesced writes
    const float p = dp[tid];                          // tid == ((b*D+d)*HW+pix): coalesced
    ekey[slot] = (gcell << 13) | (tid % HW);
    ew16[slot] = (unsigned short)__float2uint_rn(p * 65535.0f);
}

// ---- K4: chunked segmented reduction. 4 waves/block, wave = one 64-entry
// chunk, thread = 2 channels. readlane broadcasts (SGPR path). Flush:
// cells wholly owned by this chunk -> plain float2 store; cells continued
// across a chunk boundary -> atomicAdd. Byte-identical to round 7.
__global__ __launch_bounds__(256) void k_chunk_gather(
    const _Float16* __restrict__ img_t,
    const int* __restrict__ offs,     // offs[NCELL_TOT] = total entry count
    const int* __restrict__ ekey,
    const unsigned short* __restrict__ ew16,
    float* __restrict__ out_t)
{
    const int total = offs[NCELL_TOT];
    const int wave  = threadIdx.x >> 6;
    const int lane  = threadIdx.x & 63;
    const int base  = (blockIdx.x * WAVES_PER_BLK + wave) * CHUNK;
    if (base >= total) return;

    // per-lane entry fetch (coalesced); pad = dup last key, weight 0
    const int eidx = min(base + lane, total - 1);
    const int   mykey = ekey[eidx];
    const float myw   = (base + lane < total)
                        ? (float)ew16[base + lane] * (1.0f / 65535.0f) : 0.0f;
    const int mywi = __float_as_int(myw);

    const int c2 = lane * 2;                          // channels c2, c2+1
    const int fc    = __builtin_amdgcn_readlane(mykey, 0) >> 13;   // first cell
    const int lcell = __builtin_amdgcn_readlane(mykey, 63) >> 13;  // last cell
    // boundary-continuation flags (uniform scalar loads, broadcast by cache)
    const bool shared_first = (base > 0) && ((ekey[base - 1] >> 13) == fc);
    const bool shared_last  = (base + CHUNK < total) && ((ekey[base + CHUNK] >> 13) == lcell);

    int prev = fc;
    float2 acc = make_float2(0.0f, 0.0f);

#define LOADG(g, V)                                                              \
    do {                                                                         \
        _Pragma("unroll")                                                        \
        for (int k = 0; k < 8; ++k) {                                            \
            const int key = __builtin_amdgcn_readlane(mykey, (g) * 8 + k);       \
            const int pix = key & 8191;                                          \
            const int bb  = key >> 27;                                           \
            V[k] = *reinterpret_cast<const half2v*>(                             \
                &img_t[((size_t)(bb * HW + pix)) * C_DIM + c2]);                 \
        }                                                                        \
    } while (0)

#define FLUSHP(cell)                                                             \
    do {                                                                         \
        float* o = &out_t[(size_t)(cell) * C_DIM + c2];                          \
        const bool shared_ = ((cell) == fc && shared_first) ||                   \
                             ((cell) == lcell && shared_last);                   \
        if (shared_) {                                                           \
            atomicAdd(o, acc.x);                                                 \
            atomicAdd(o + 1, acc.y);                                             \
        } else {                                                                 \
            *reinterpret_cast<float2*>(o) = acc;  /* exclusive owner */          \
        }                                                                        \
    } while (0)

#define ACCG(g, V)                                                               \
    do {                                                                         \
        _Pragma("unroll")                                                        \
        for (int k = 0; k < 8; ++k) {                                            \
            const int   key = __builtin_amdgcn_readlane(mykey, (g) * 8 + k);     \
            const float wgt =                                                    \
                __int_as_float(__builtin_amdgcn_readlane(mywi, (g) * 8 + k));    \
            const int gcell = key >> 13;                                         \
            if (gcell != prev) {                      /* scalar branch */        \
                FLUSHP(prev);                                                    \
                acc = make_float2(0.0f, 0.0f);                                   \
                prev = gcell;                                                    \
            }                                                                    \
            acc.x = fmaf((float)V[k][0], wgt, acc.x);                            \
            acc.y = fmaf((float)V[k][1], wgt, acc.y);                            \
        }                                                                        \
    } while (0)

    half2v va[8], vb[8];
    // modulo-2 software pipeline over 8 groups of 8 entries (CHUNK=64)
    LOADG(0, va);
    LOADG(1, vb);
    ACCG(0, va);
    LOADG(2, va);
    ACCG(1, vb);
    LOADG(3, vb);
    ACCG(2, va);
    LOADG(4, va);
    ACCG(3, vb);
    LOADG(5, vb);
    ACCG(4, va);
    LOADG(6, va);
    ACCG(5, vb);
    LOADG(7, vb);
    ACCG(6, va);
    ACCG(7, vb);
    FLUSHP(prev);

#undef LOADG
#undef FLUSHP
#undef ACCG
}

// ---- K5: untranspose out_t[b][cell][c] -> out[b][c][cell] ----
__global__ __launch_bounds__(256) void k_untranspose(const float* __restrict__ out_t,
                                                     float* __restrict__ out) {
    __shared__ float tile[32][33];
    const int b = blockIdx.z;
    const int tx = threadIdx.x, ty = threadIdx.y;      // block (32, 8)
    const int cell0 = blockIdx.x * 32, c0 = blockIdx.y * 32;
    const float* src = out_t + (size_t)b * NCELL * C_DIM;
    #pragma unroll
    for (int j = 0; j < 32; j += 8)                    // read: c contiguous
        tile[ty + j][tx] = src[((size_t)(cell0 + ty + j)) * C_DIM + c0 + tx];
    __syncthreads();
    #pragma unroll
    for (int j = 0; j < 32; j += 8)                    // write: cell contiguous
        out[((size_t)(b * C_DIM + c0 + ty + j)) * NCELL + cell0 + tx] = tile[tx][ty + j];
}

extern "C" void kernel_launch(void* const* d_in, const int* in_sizes, int n_in,
                              void* d_out, int out_size, void* d_ws, size_t ws_size,
                              hipStream_t stream) {
    const float* img = (const float*)d_in[0];
    const float* dp  = (const float*)d_in[1];
    const float* dv  = (const float*)d_in[2];
    const float* K   = (const float*)d_in[3];
    const float* T   = (const float*)d_in[4];
    float* out = (float*)d_out;

    _Float16* img_t = (_Float16*)d_ws;                  // WS_IMG_T == 0
    int*   tot    = (int*)d_ws + WS_TOT;
    int*   hist2  = (int*)d_ws + WS_HIST2;
    float* out_t  = (float*)d_ws + WS_OUT_T;
    int*   offs   = (int*)d_ws + WS_OFFS;
    int*   ekey   = (int*)d_ws + WS_EKEY;
    unsigned short* ew16 = (unsigned short*)((int*)d_ws + WS_EW16);
    (void)ws_size;

    // zero tot + hist2 (contiguous, ~2.1 MB); out_t zeroed inside k_prep
    hipMemsetAsync(tot, 0, MEMSET_WORDS * sizeof(int), stream);

    k_prep<<<PREP_TOTAL, 256, 0, stream>>>(img, img_t, dv, K, T, hist2,
                                           (float4*)out_t);
    k_scan<<<SCAN_BLOCKS, 256, 0, stream>>>(hist2, offs, tot);
    k_fill<<<NPTS / 256, 256, 0, stream>>>(dp, dv, K, T, offs, hist2, ekey, ew16);
    constexpr int GATHER_BLOCKS = MAX_ENTRIES / (CHUNK * WAVES_PER_BLK);
    k_chunk_gather<<<GATHER_BLOCKS, 256, 0, stream>>>(img_t, offs, ekey, ew16, out_t);
    k_untranspose<<<dim3(NCELL / 32, C_DIM / 32, B_DIM), dim3(32, 8), 0, stream>>>(
        out_t, out);
}